// Round 1
// baseline (1230.673 us; speedup 1.0000x reference)
//
#include <hip/hip_runtime.h>
#include <hip/hip_bf16.h>
#include <math.h>

typedef __bf16 bf16x8 __attribute__((ext_vector_type(8)));
typedef float f32x4 __attribute__((ext_vector_type(4)));
typedef unsigned short u16;
typedef unsigned int u32;

#define TOKENS 16384
#define MROWS  65536

__device__ __forceinline__ u16 f2bf(float f) {
  union { __hip_bfloat16 h; u16 u; } c;
  c.h = __float2bfloat16(f);
  return c.u;
}
__device__ __forceinline__ float bf2f(u16 u) {
  union { u16 u; __hip_bfloat16 h; } c;
  c.u = u;
  return __bfloat162float(c.h);
}

// ---------------- prep kernels ----------------
// G[c][c2] = (1/sqrt(512)) * sum_d Wq[c][d] * Wk[c2][d]     (128x128 fp32)
__global__ void kprep_G(const float* __restrict__ Wq, const float* __restrict__ Wk,
                        float* __restrict__ G) {
  int id = blockIdx.x * 256 + threadIdx.x;  // 16384
  int c = id >> 7, c2 = id & 127;
  const float4* a = (const float4*)(Wq + (size_t)c * 512);
  const float4* b = (const float4*)(Wk + (size_t)c2 * 512);
  float s = 0.f;
#pragma unroll 8
  for (int i = 0; i < 128; ++i) {
    float4 xa = a[i], yb = b[i];
    s += xa.x * yb.x + xa.y * yb.y + xa.z * yb.z + xa.w * yb.w;
  }
  G[id] = s * 0.044194173824159216f;
}

// WvpT[e][c] = bf16( sum_d Wv[c][d] * Wp[d][e] )   (512x128, B^T layout)
__global__ void kprep_Wvp(const float* __restrict__ Wv, const float* __restrict__ Wp,
                          u16* __restrict__ WvpT) {
  int id = blockIdx.x * 256 + threadIdx.x;  // 65536 : e*128+c
  int e = id >> 7, c = id & 127;
  float s = 0.f;
#pragma unroll 4
  for (int d = 0; d < 512; ++d) s += Wv[(size_t)c * 512 + d] * Wp[(size_t)d * 512 + e];
  WvpT[id] = f2bf(s);
}

// W1T[f][e] = bf16(W1[e][f])   (2048x512)
__global__ void kprep_W1T(const float* __restrict__ W1, u16* __restrict__ W1T) {
  int id = blockIdx.x * 256 + threadIdx.x;  // 1M : f*512+e
  int f = id >> 9, e = id & 511;
  W1T[id] = f2bf(W1[(size_t)e * 2048 + f]);
}
// W2T[e][f] = bf16(W2[f][e])   (512x2048)
__global__ void kprep_W2T(const float* __restrict__ W2, u16* __restrict__ W2T) {
  int id = blockIdx.x * 256 + threadIdx.x;  // 1M : e*2048+f
  int e = id >> 11, f = id & 2047;
  W2T[id] = f2bf(W2[(size_t)f * 512 + e]);
}

// ---------------- token attention: Z = softmax(mask(S G S^T)) S ----------------
// one wave per token; 4 tokens per 256-thread block
__global__ __launch_bounds__(256) void ktoken(const float* __restrict__ x,
                                              const float* __restrict__ G,
                                              u16* __restrict__ Z) {
  __shared__ float Ss[4 * 512];   // [tok][i*128+c]
  __shared__ float T1s[4 * 512];  // [tok][i*128+c2]
  __shared__ float Ws[4 * 16];    // [tok][i*4+j]
  int tid = threadIdx.x;
  int wave = tid >> 6, lane = tid & 63;
  int tok0 = blockIdx.x * 4;
  // load S rows (4 tokens x 512 f32)
  {
    const float4* xsrc = (const float4*)(x + (size_t)tok0 * 512);
    float4* sdst = (float4*)Ss;
    sdst[tid] = xsrc[tid];
    sdst[256 + tid] = xsrc[256 + tid];
  }
  __syncthreads();
  // T1 = S @ G : each lane computes cols (2*lane, 2*lane+1) for 4 rows
  {
    const float* Sw = Ss + wave * 512;
    float a00 = 0, a01 = 0, a10 = 0, a11 = 0, a20 = 0, a21 = 0, a30 = 0, a31 = 0;
#pragma unroll 4
    for (int c = 0; c < 128; ++c) {
      float2 gg = ((const float2*)(G + (size_t)c * 128))[lane];
      float s0 = Sw[c], s1 = Sw[128 + c], s2 = Sw[256 + c], s3 = Sw[384 + c];
      a00 += s0 * gg.x; a01 += s0 * gg.y;
      a10 += s1 * gg.x; a11 += s1 * gg.y;
      a20 += s2 * gg.x; a21 += s2 * gg.y;
      a30 += s3 * gg.x; a31 += s3 * gg.y;
    }
    float* Tw = T1s + wave * 512;
    int c2 = lane * 2;
    Tw[c2] = a00; Tw[c2 + 1] = a01;
    Tw[128 + c2] = a10; Tw[128 + c2 + 1] = a11;
    Tw[256 + c2] = a20; Tw[256 + c2 + 1] = a21;
    Tw[384 + c2] = a30; Tw[384 + c2 + 1] = a31;
  }
  __syncthreads();
  // wei[i][j] = T1[i] . S[j]
  if (lane < 16) {
    int i = lane >> 2, j = lane & 3;
    const float* Tw = T1s + wave * 512 + i * 128;
    const float* Sw = Ss + wave * 512 + j * 128;
    float d = 0.f;
#pragma unroll 8
    for (int c = 0; c < 128; ++c) d += Tw[c] * Sw[c];
    Ws[wave * 16 + i * 4 + j] = d;
  }
  __syncthreads();
  // softmax (causal over head idx) + Z = P @ S
  {
    float p[4][4];
    const float* ww = Ws + wave * 16;
#pragma unroll
    for (int i = 0; i < 4; ++i) {
      float m = -1e30f;
      for (int j = 0; j <= i; ++j) m = fmaxf(m, ww[i * 4 + j]);
      float s = 0.f;
      for (int j = 0; j <= i; ++j) { p[i][j] = __expf(ww[i * 4 + j] - m); s += p[i][j]; }
      float inv = 1.f / s;
      for (int j = 0; j <= i; ++j) p[i][j] *= inv;
      for (int j = i + 1; j < 4; ++j) p[i][j] = 0.f;
    }
    const float* Sw = Ss + wave * 512;
    int c = lane * 2;
    u32* zout = (u32*)(Z + (size_t)(tok0 + wave) * 512);
#pragma unroll
    for (int i = 0; i < 4; ++i) {
      float z0 = 0.f, z1 = 0.f;
#pragma unroll
      for (int j = 0; j < 4; ++j) {
        z0 += p[i][j] * Sw[j * 128 + c];
        z1 += p[i][j] * Sw[j * 128 + c + 1];
      }
      zout[i * 64 + lane] = (u32)f2bf(z0) | ((u32)f2bf(z1) << 16);
    }
  }
}

// ---------------- attn-out projection + bias + residual + LN1 -> X1 (bf16) ----------------
// block: 64 rows x 512 cols (full row -> LN fusable). 8 waves (2M x 4N), wave tile 32x128.
__global__ __launch_bounds__(512) void kattn(const u16* __restrict__ Z,
                                             const u16* __restrict__ WvpT,
                                             const float* __restrict__ bp,
                                             const float* __restrict__ x,
                                             const float* __restrict__ g1,
                                             const float* __restrict__ bln1,
                                             u16* __restrict__ X1) {
  __shared__ u16 AO[32768];          // 64KB: first 16KB = A tile (swizzled); reused as out-stage
  __shared__ float rsum[64 * 4];
  __shared__ float rsq[64 * 4];
  __shared__ float mus[64];
  __shared__ float rss[64];
  char* smem = (char*)AO;
  int tid = threadIdx.x;
  int lane = tid & 63, wid = tid >> 6;
  int wm = wid >> 2, wnq = wid & 3;
  int lane_lo = lane & 15, lane_hi = lane >> 4;
  int m0 = blockIdx.x * 64;
  // stage A tile: Z rows m0..m0+63, [64][128] bf16, swizzled
  {
    const bf16x8* src = (const bf16x8*)(Z + (size_t)m0 * 128);
#pragma unroll
    for (int it = 0; it < 2; ++it) {
      int idx8 = it * 512 + tid;     // 16B units, 1024 total (16 per row)
      int row = idx8 >> 4;
      int byte = (idx8 * 16) ^ ((row & 7) << 4);
      *(bf16x8*)(smem + byte) = src[idx8];
    }
  }
  __syncthreads();
  f32x4 acc[2][8];
#pragma unroll
  for (int mi = 0; mi < 2; ++mi)
#pragma unroll
    for (int ni = 0; ni < 8; ++ni) acc[mi][ni] = (f32x4){0.f, 0.f, 0.f, 0.f};
#pragma unroll
  for (int ks = 0; ks < 4; ++ks) {
    bf16x8 af[2];
#pragma unroll
    for (int mi = 0; mi < 2; ++mi) {
      int row = wm * 32 + mi * 16 + lane_lo;
      int byte = (row * 256 + (ks * 32 + lane_hi * 8) * 2) ^ ((row & 7) << 4);
      af[mi] = *(const bf16x8*)(smem + byte);
    }
#pragma unroll
    for (int ni = 0; ni < 8; ++ni) {
      int n = wnq * 128 + ni * 16 + lane_lo;
      bf16x8 bfr = *(const bf16x8*)(WvpT + (size_t)n * 128 + ks * 32 + lane_hi * 8);
#pragma unroll
      for (int mi = 0; mi < 2; ++mi)
        acc[mi][ni] = __builtin_amdgcn_mfma_f32_16x16x32_bf16(af[mi], bfr, acc[mi][ni], 0, 0, 0);
    }
  }
  // epilogue: v = acc + bp[col] + x[token][col]; row stats
#pragma unroll
  for (int mi = 0; mi < 2; ++mi) {
#pragma unroll
    for (int j = 0; j < 4; ++j) {
      int rl = wm * 32 + mi * 16 + lane_hi * 4 + j;
      int R = m0 + rl;
      const float* xrow = x + (size_t)(R >> 2) * 512;
      float s = 0.f, q = 0.f;
#pragma unroll
      for (int ni = 0; ni < 8; ++ni) {
        int col = wnq * 128 + ni * 16 + lane_lo;
        float val = acc[mi][ni][j] + bp[col] + xrow[col];
        acc[mi][ni][j] = val;
        s += val; q += val * val;
      }
#pragma unroll
      for (int off = 1; off < 16; off <<= 1) { s += __shfl_xor(s, off); q += __shfl_xor(q, off); }
      if (lane_lo == 0) { rsum[rl * 4 + wnq] = s; rsq[rl * 4 + wnq] = q; }
    }
  }
  __syncthreads();
  if (tid < 64) {
    float s = rsum[tid * 4] + rsum[tid * 4 + 1] + rsum[tid * 4 + 2] + rsum[tid * 4 + 3];
    float q = rsq[tid * 4] + rsq[tid * 4 + 1] + rsq[tid * 4 + 2] + rsq[tid * 4 + 3];
    float mu = s * (1.f / 512.f);
    float var = q * (1.f / 512.f) - mu * mu;
    mus[tid] = mu;
    rss[tid] = rsqrtf(var + 512.0f);
  }
  __syncthreads();
  // normalize -> out-stage (linear [64][512] bf16, overwrites A region)
#pragma unroll
  for (int mi = 0; mi < 2; ++mi) {
#pragma unroll
    for (int j = 0; j < 4; ++j) {
      int rl = wm * 32 + mi * 16 + lane_hi * 4 + j;
      float mu = mus[rl], rs = rss[rl];
#pragma unroll
      for (int ni = 0; ni < 8; ++ni) {
        int col = wnq * 128 + ni * 16 + lane_lo;
        AO[rl * 512 + col] = f2bf((acc[mi][ni][j] - mu) * rs * g1[col] + bln1[col]);
      }
    }
  }
  __syncthreads();
  // coalesced 64KB write
  {
    bf16x8* dst = (bf16x8*)(X1 + (size_t)m0 * 512);
    const bf16x8* s8 = (const bf16x8*)AO;
#pragma unroll
    for (int it = 0; it < 8; ++it) dst[it * 512 + tid] = s8[it * 512 + tid];
  }
}

// ---------------- fused MLP: out = LN2( X1 + gelu(X1 W1 + b1) W2 + b2 ) ----------------
// block: 64 rows x 512 cols; hidden (2048) processed in 16 chunks of 128.
__global__ __launch_bounds__(512) void kmlp(const u16* __restrict__ X1,
                                            const u16* __restrict__ W1T,
                                            const u16* __restrict__ W2T,
                                            const float* __restrict__ b1v,
                                            const float* __restrict__ b2v,
                                            const float* __restrict__ g2,
                                            const float* __restrict__ bln2,
                                            float* __restrict__ out) {
  __shared__ u16 Abuf[32768];  // 64KB: X1 tile [64][512] bf16, swizzled
  __shared__ u16 Hbuf[8192];   // 16KB: Hc [64][128] bf16, swizzled
  __shared__ float rsum[64 * 4];
  __shared__ float rsq[64 * 4];
  __shared__ float mus[64];
  __shared__ float rss[64];
  char* Abase = (char*)Abuf;
  char* Hbase = (char*)Hbuf;
  int tid = threadIdx.x;
  int lane = tid & 63, wid = tid >> 6;
  int wm = wid >> 2, wnq = wid & 3;
  int lane_lo = lane & 15, lane_hi = lane >> 4;
  int m0 = blockIdx.x * 64;
  // stage X1 tile (64x512 bf16 = 64KB), swizzled
  {
    const bf16x8* src = (const bf16x8*)(X1 + (size_t)m0 * 512);
#pragma unroll
    for (int it = 0; it < 8; ++it) {
      int idx8 = it * 512 + tid;  // 4096 16B-units (64 per row)
      int row = idx8 >> 6;
      int byte = (idx8 * 16) ^ ((row & 7) << 4);
      *(bf16x8*)(Abase + byte) = src[idx8];
    }
  }
  __syncthreads();
  f32x4 accO[2][8];
#pragma unroll
  for (int mi = 0; mi < 2; ++mi)
#pragma unroll
    for (int ni = 0; ni < 8; ++ni) accO[mi][ni] = (f32x4){0.f, 0.f, 0.f, 0.f};

  for (int ch = 0; ch < 16; ++ch) {
    // FF1 chunk: Hc[64][128] = gelu(A @ W1[:, ch*128..+128] + b1); wave tile 32x32
    f32x4 acc1[2][2];
#pragma unroll
    for (int mi = 0; mi < 2; ++mi)
#pragma unroll
      for (int ni = 0; ni < 2; ++ni) acc1[mi][ni] = (f32x4){0.f, 0.f, 0.f, 0.f};
#pragma unroll
    for (int ks = 0; ks < 16; ++ks) {
      bf16x8 af[2];
#pragma unroll
      for (int mi = 0; mi < 2; ++mi) {
        int row = wm * 32 + mi * 16 + lane_lo;
        int byte = (row * 1024 + (ks * 32 + lane_hi * 8) * 2) ^ ((row & 7) << 4);
        af[mi] = *(const bf16x8*)(Abase + byte);
      }
#pragma unroll
      for (int ni = 0; ni < 2; ++ni) {
        int n = ch * 128 + wnq * 32 + ni * 16 + lane_lo;
        bf16x8 bfr = *(const bf16x8*)(W1T + (size_t)n * 512 + ks * 32 + lane_hi * 8);
#pragma unroll
        for (int mi = 0; mi < 2; ++mi)
          acc1[mi][ni] = __builtin_amdgcn_mfma_f32_16x16x32_bf16(af[mi], bfr, acc1[mi][ni], 0, 0, 0);
      }
    }
    __syncthreads();  // prior FF2 reads of Hbuf complete
    // gelu -> Hc (bf16, swizzled)
#pragma unroll
    for (int mi = 0; mi < 2; ++mi)
#pragma unroll
      for (int ni = 0; ni < 2; ++ni)
#pragma unroll
        for (int j = 0; j < 4; ++j) {
          int rl = wm * 32 + mi * 16 + lane_hi * 4 + j;
          int col = wnq * 32 + ni * 16 + lane_lo;
          float u = acc1[mi][ni][j] + b1v[ch * 128 + col];
          float ge = 0.5f * u * (1.f + erff(u * 0.70710678118654752f));
          int byte = (rl * 256 + col * 2) ^ ((rl & 7) << 4);
          *(u16*)(Hbase + byte) = f2bf(ge);
        }
    __syncthreads();
    // FF2 accumulate: accO += Hc @ W2[ch*128..+128, :]; wave tile 32x128
#pragma unroll
    for (int ks = 0; ks < 4; ++ks) {
      bf16x8 ah[2];
#pragma unroll
      for (int mi = 0; mi < 2; ++mi) {
        int row = wm * 32 + mi * 16 + lane_lo;
        int byte = (row * 256 + (ks * 32 + lane_hi * 8) * 2) ^ ((row & 7) << 4);
        ah[mi] = *(const bf16x8*)(Hbase + byte);
      }
#pragma unroll
      for (int ni = 0; ni < 8; ++ni) {
        int n = wnq * 128 + ni * 16 + lane_lo;
        bf16x8 bfr = *(const bf16x8*)(W2T + (size_t)n * 2048 + ch * 128 + ks * 32 + lane_hi * 8);
#pragma unroll
        for (int mi = 0; mi < 2; ++mi)
          accO[mi][ni] = __builtin_amdgcn_mfma_f32_16x16x32_bf16(ah[mi], bfr, accO[mi][ni], 0, 0, 0);
      }
    }
  }
  // epilogue: + b2 + x1 residual, LN2, fp32 out
#pragma unroll
  for (int mi = 0; mi < 2; ++mi) {
#pragma unroll
    for (int j = 0; j < 4; ++j) {
      int rl = wm * 32 + mi * 16 + lane_hi * 4 + j;
      float s = 0.f, q = 0.f;
#pragma unroll
      for (int ni = 0; ni < 8; ++ni) {
        int col = wnq * 128 + ni * 16 + lane_lo;
        int abyte = (rl * 1024 + col * 2) ^ ((rl & 7) << 4);
        float x1v = bf2f(*(const u16*)(Abase + abyte));
        float val = accO[mi][ni][j] + b2v[col] + x1v;
        accO[mi][ni][j] = val;
        s += val; q += val * val;
      }
#pragma unroll
      for (int off = 1; off < 16; off <<= 1) { s += __shfl_xor(s, off); q += __shfl_xor(q, off); }
      if (lane_lo == 0) { rsum[rl * 4 + wnq] = s; rsq[rl * 4 + wnq] = q; }
    }
  }
  __syncthreads();
  if (tid < 64) {
    float s = rsum[tid * 4] + rsum[tid * 4 + 1] + rsum[tid * 4 + 2] + rsum[tid * 4 + 3];
    float q = rsq[tid * 4] + rsq[tid * 4 + 1] + rsq[tid * 4 + 2] + rsq[tid * 4 + 3];
    float mu = s * (1.f / 512.f);
    float var = q * (1.f / 512.f) - mu * mu;
    mus[tid] = mu;
    rss[tid] = rsqrtf(var + 512.0f);
  }
  __syncthreads();
#pragma unroll
  for (int mi = 0; mi < 2; ++mi) {
#pragma unroll
    for (int j = 0; j < 4; ++j) {
      int rl = wm * 32 + mi * 16 + lane_hi * 4 + j;
      float mu = mus[rl], rs = rss[rl];
      float* orow = out + (size_t)(m0 + rl) * 512;
#pragma unroll
      for (int ni = 0; ni < 8; ++ni) {
        int col = wnq * 128 + ni * 16 + lane_lo;
        orow[col] = (accO[mi][ni][j] - mu) * rs * g2[col] + bln2[col];
      }
    }
  }
}

extern "C" void kernel_launch(void* const* d_in, const int* in_sizes, int n_in,
                              void* d_out, int out_size, void* d_ws, size_t ws_size,
                              hipStream_t stream) {
  const float* x   = (const float*)d_in[0];
  const float* Wq  = (const float*)d_in[1];
  const float* Wk  = (const float*)d_in[2];
  const float* Wv  = (const float*)d_in[3];
  const float* Wp  = (const float*)d_in[4];
  const float* bp  = (const float*)d_in[5];
  const float* W1  = (const float*)d_in[6];
  const float* b1  = (const float*)d_in[7];
  const float* W2  = (const float*)d_in[8];
  const float* b2  = (const float*)d_in[9];
  const float* g1  = (const float*)d_in[10];
  const float* bb1 = (const float*)d_in[11];
  const float* g2  = (const float*)d_in[12];
  const float* bb2 = (const float*)d_in[13];
  float* out = (float*)d_out;

  char* ws = (char*)d_ws;
  float* G  = (float*)ws;                    // 64KB (128x128 f32) region reserved 256KB
  u16* WvpT = (u16*)(ws + (256 << 10));      // 128KB
  u16* W1T  = (u16*)(ws + (1 << 20));        // 2MB
  u16* W2T  = (u16*)(ws + (3 << 20));        // 2MB
  u16* Z    = (u16*)(ws + (5 << 20));        // 16MB  (65536 x 128 bf16)
  u16* X1   = (u16*)(ws + (21 << 20));       // 64MB  (65536 x 512 bf16)

  hipLaunchKernelGGL(kprep_G,   dim3(64),   dim3(256), 0, stream, Wq, Wk, G);
  hipLaunchKernelGGL(kprep_Wvp, dim3(256),  dim3(256), 0, stream, Wv, Wp, WvpT);
  hipLaunchKernelGGL(kprep_W1T, dim3(4096), dim3(256), 0, stream, W1, W1T);
  hipLaunchKernelGGL(kprep_W2T, dim3(4096), dim3(256), 0, stream, W2, W2T);
  hipLaunchKernelGGL(ktoken,    dim3(4096), dim3(256), 0, stream, x, G, Z);
  hipLaunchKernelGGL(kattn,     dim3(1024), dim3(512), 0, stream, Z, WvpT, bp, x, g1, bb1, X1);
  hipLaunchKernelGGL(kmlp,      dim3(1024), dim3(512), 0, stream, X1, W1T, W2T, b1, b2, g2, bb2, out);
}